// Round 5
// baseline (572.045 us; speedup 1.0000x reference)
//
#include <hip/hip_runtime.h>

// Problem constants (from reference setup_inputs)
constexpr int kB = 256;
constexpr int kT = 2048;
constexpr int kI = 32;
constexpr int kH = 64;
constexpr int kO = 16;
constexpr int kPadL = 2;
constexpr int kPadR = 3;
constexpr int kTp = kT + kPadL + kPadR;  // 2053
constexpr int kCT = 64;                  // timesteps per producer chunk
constexpr int kNC = kT / kCT;            // 32 chunks

constexpr float kS = 1.4426950408889634f;  // log2(e), folded into weights

// Dynamic-LDS byte layout (no static __shared__, so offsets start at 0):
//   [0, 128)            rbuf : 64 x f16 broadcast of r
//   [128, 128+2*16384)  xinbuf: 2 x (64 t x 64 h) f32, double-buffered
//   [32896, 33152)      aggbuf: 64 x f32 (epilogue)
constexpr unsigned kRbufOff  = 0;
constexpr unsigned kXinOff   = 128;
constexpr unsigned kXinBytes = kCT * kH * 4;            // 16384
constexpr unsigned kAggOff   = kXinOff + 2 * kXinBytes; // 32896
constexpr unsigned kSmemBytes = kAggOff + kH * 4;       // 33152

typedef float    v2f __attribute__((ext_vector_type(2)));
typedef _Float16 v2h __attribute__((ext_vector_type(2)));
typedef unsigned v4u __attribute__((ext_vector_type(4)));

extern __shared__ char smem[];

__device__ __forceinline__ void pk_fma(v2f& d, v2f a, v2f b) {
  asm("v_pk_fma_f32 %0, %1, %2, %0" : "+v"(d) : "v"(a), "v"(b));
}

__device__ __forceinline__ v2h as_h2(unsigned u) {
  return __builtin_bit_cast(v2h, u);
}

__device__ __forceinline__ float dot2(v2h a, v2h b, float c) {
#if __has_builtin(__builtin_amdgcn_fdot2)
  return __builtin_amdgcn_fdot2(a, b, c, false);
#else
  return fmaf((float)a.x, (float)b.x, fmaf((float)a.y, (float)b.y, c));
#endif
}

__device__ __forceinline__ float exp2_fast(float x) {
#if __has_builtin(__builtin_amdgcn_exp2f)
  return __builtin_amdgcn_exp2f(x);
#else
  return exp2f(x);
#endif
}

// Per-step LDS traffic in ONE volatile asm block so the compiler cannot
// insert a write-drain waitcnt between the r-write and the r-reads.
// Same-wave DS ops execute in order, so the b128 reads observe the b16 write.
// MAIN variant also prefetches next step's xin (ds_read_b32).
#define STEP_LDS_MAIN(q0, q1, q2, q3, q4, q5, q6, q7, xn, rv, xaddr)  \
  asm volatile(                                                       \
      "ds_write_b16 %9, %10\n\t"                                      \
      "ds_read_b128 %0, %11 offset:0\n\t"                             \
      "ds_read_b128 %1, %11 offset:16\n\t"                            \
      "ds_read_b128 %2, %11 offset:32\n\t"                            \
      "ds_read_b128 %3, %11 offset:48\n\t"                            \
      "ds_read_b128 %4, %11 offset:64\n\t"                            \
      "ds_read_b128 %5, %11 offset:80\n\t"                            \
      "ds_read_b128 %6, %11 offset:96\n\t"                            \
      "ds_read_b128 %7, %11 offset:112\n\t"                           \
      "ds_read_b32 %8, %12\n\t"                                       \
      "s_waitcnt lgkmcnt(0)"                                          \
      : "=v"(q0), "=v"(q1), "=v"(q2), "=v"(q3),                       \
        "=v"(q4), "=v"(q5), "=v"(q6), "=v"(q7), "=v"(xn)              \
      : "v"(raddr), "v"(rv), "v"(rbase), "v"(xaddr))

#define STEP_LDS_NOX(q0, q1, q2, q3, q4, q5, q6, q7, rv)              \
  asm volatile(                                                       \
      "ds_write_b16 %8, %9\n\t"                                       \
      "ds_read_b128 %0, %10 offset:0\n\t"                             \
      "ds_read_b128 %1, %10 offset:16\n\t"                            \
      "ds_read_b128 %2, %10 offset:32\n\t"                            \
      "ds_read_b128 %3, %10 offset:48\n\t"                            \
      "ds_read_b128 %4, %10 offset:64\n\t"                            \
      "ds_read_b128 %5, %10 offset:80\n\t"                            \
      "ds_read_b128 %6, %10 offset:96\n\t"                            \
      "ds_read_b128 %7, %10 offset:112\n\t"                           \
      "s_waitcnt lgkmcnt(0)"                                          \
      : "=v"(q0), "=v"(q1), "=v"(q2), "=v"(q3),                       \
        "=v"(q4), "=v"(q5), "=v"(q6), "=v"(q7)                        \
      : "v"(raddr), "v"(rv), "v"(rbase))

__global__ __launch_bounds__(128) void rnn_fused(
    const float* __restrict__ x,
    const float* __restrict__ W_ih,
    const float* __restrict__ W_hh,
    const float* __restrict__ b_ih,
    const float* __restrict__ b_hh,
    const float* __restrict__ W_fc,
    const float* __restrict__ b_fc,
    float* __restrict__ out)
{
  const int b = blockIdx.x;
  const int lane = threadIdx.x & 63;   // hidden unit index
  const int wave = threadIdx.x >> 6;

  // bias' = 2*kS*(b_ih + b_hh + rowsum(W_hh row lane))
  float rowsum = 0.0f;
#pragma unroll
  for (int j = 0; j < kH; j += 4) {
    float4 v = *(const float4*)(W_hh + lane * kH + j);
    rowsum += (v.x + v.y) + (v.z + v.w);
  }
  const float bias2 = 2.0f * kS * (b_ih[lane] + b_hh[lane] + rowsum);

  if (wave == 1) {
    // ================= producer (normal HIP; own SIMD) =================
    v2f wi2[kI / 2];  // 2*kS*W_ih[lane][i]
#pragma unroll
    for (int i = 0; i < kI; i += 4) {
      float4 v = *(const float4*)(W_ih + lane * kI + i);
      wi2[i / 2 + 0] = v2f{2.0f * kS * v.x, 2.0f * kS * v.y};
      wi2[i / 2 + 1] = v2f{2.0f * kS * v.z, 2.0f * kS * v.w};
    }
    const float* xb = x + (size_t)b * kT * kI;

    auto fill = [&](int c, int buf) {
      const float* src = xb + (size_t)c * kCT * kI;
      float* dst = (float*)(smem + kXinOff + buf * kXinBytes);
#pragma unroll 2
      for (int t = 0; t < kCT; ++t) {
        const float4* row = (const float4*)(src + t * kI);  // broadcast loads
        v2f a0 = v2f{0.0f, 0.0f}, a1 = v2f{0.0f, 0.0f};
#pragma unroll
        for (int i2 = 0; i2 < 8; ++i2) {
          float4 v = row[i2];
          pk_fma(a0, wi2[2 * i2 + 0], v2f{v.x, v.y});
          pk_fma(a1, wi2[2 * i2 + 1], v2f{v.z, v.w});
        }
        dst[t * kH + lane] = bias2 + ((a0.x + a0.y) + (a1.x + a1.y));
      }
    };

    fill(0, 0);
    __syncthreads();  // buffer 0 ready
    for (int c = 0; c < kNC; ++c) {
      if (c + 1 < kNC) fill(c + 1, (c + 1) & 1);
      __syncthreads();  // end of chunk c
    }
    return;
  }

  // ================= consumer (wave 0) =================
  v2h wh[kH / 2];  // -4*kS*W_hh[lane][j] as fp16 pairs
#pragma unroll
  for (int j = 0; j < kH; j += 2) {
    float w0 = W_hh[lane * kH + j + 0];
    float w1 = W_hh[lane * kH + j + 1];
    wh[j / 2] = v2h{(_Float16)(-4.0f * kS * w0), (_Float16)(-4.0f * kS * w1)};
  }

  const unsigned raddr = kRbufOff + (unsigned)lane * 2u;  // this lane's r slot
  unsigned rbase = kRbufOff;                              // broadcast base (0)

  float rsum = 0.0f;
  unsigned rv = (unsigned)__builtin_bit_cast(unsigned short, (_Float16)0.5f);

  // dots + tail: z' = za_init + sum_j wh[j]*r_j ; r = 1/(1+2^{z'})
  auto tail = [&](const v4u& A, const v4u& B, const v4u& C, const v4u& D,
                  const v4u& E, const v4u& F, const v4u& G, const v4u& H,
                  float za_init) -> float {
    float za = za_init, zb = 0.0f, zc = 0.0f, zd = 0.0f;
    za = dot2(as_h2(A.x), wh[0], za);
    zb = dot2(as_h2(A.y), wh[1], zb);
    zc = dot2(as_h2(A.z), wh[2], zc);
    zd = dot2(as_h2(A.w), wh[3], zd);
    za = dot2(as_h2(B.x), wh[4], za);
    zb = dot2(as_h2(B.y), wh[5], zb);
    zc = dot2(as_h2(B.z), wh[6], zc);
    zd = dot2(as_h2(B.w), wh[7], zd);
    za = dot2(as_h2(C.x), wh[8], za);
    zb = dot2(as_h2(C.y), wh[9], zb);
    zc = dot2(as_h2(C.z), wh[10], zc);
    zd = dot2(as_h2(C.w), wh[11], zd);
    za = dot2(as_h2(D.x), wh[12], za);
    zb = dot2(as_h2(D.y), wh[13], zb);
    zc = dot2(as_h2(D.z), wh[14], zc);
    zd = dot2(as_h2(D.w), wh[15], zd);
    za = dot2(as_h2(E.x), wh[16], za);
    zb = dot2(as_h2(E.y), wh[17], zb);
    zc = dot2(as_h2(E.z), wh[18], zc);
    zd = dot2(as_h2(E.w), wh[19], zd);
    za = dot2(as_h2(F.x), wh[20], za);
    zb = dot2(as_h2(F.y), wh[21], zb);
    zc = dot2(as_h2(F.z), wh[22], zc);
    zd = dot2(as_h2(F.w), wh[23], zd);
    za = dot2(as_h2(G.x), wh[24], za);
    zb = dot2(as_h2(G.y), wh[25], zb);
    zc = dot2(as_h2(G.z), wh[26], zc);
    zd = dot2(as_h2(G.w), wh[27], zd);
    za = dot2(as_h2(H.x), wh[28], za);
    zb = dot2(as_h2(H.y), wh[29], zb);
    zc = dot2(as_h2(H.z), wh[30], zc);
    zd = dot2(as_h2(H.w), wh[31], zd);
    float z2 = (za + zb) + (zc + zd);   // = 2*z*log2e
    float t = exp2_fast(z2);            // e^{2z}; inf -> r = 0 (graceful)
    return __builtin_amdgcn_rcpf(1.0f + t);
  };

  auto pad_step = [&]() {
    v4u q0, q1, q2, q3, q4, q5, q6, q7;
    STEP_LDS_NOX(q0, q1, q2, q3, q4, q5, q6, q7, rv);
    float r = tail(q0, q1, q2, q3, q4, q5, q6, q7, bias2);
    rsum += r;
    rv = (unsigned)__builtin_bit_cast(unsigned short, (_Float16)r);
  };

  // left padding (runs while producer fills buffer 0)
  pad_step();
  pad_step();
  __syncthreads();  // buffer 0 ready

  for (int c = 0; c < kNC; ++c) {
    const unsigned xbase = kXinOff + (unsigned)(c & 1) * kXinBytes +
                           (unsigned)lane * 4u;
    // prime this chunk's first xin (post-barrier, so no race with producer)
    float xc;
    asm volatile("ds_read_b32 %0, %1\n\ts_waitcnt lgkmcnt(0)"
                 : "=v"(xc) : "v"(xbase));
#pragma unroll 9
    for (int t = 0; t < kCT - 1; ++t) {
      v4u q0, q1, q2, q3, q4, q5, q6, q7;
      float xn;
      const unsigned xaddr = xbase + (unsigned)(t + 1) * (kH * 4u);
      STEP_LDS_MAIN(q0, q1, q2, q3, q4, q5, q6, q7, xn, rv, xaddr);
      float r = tail(q0, q1, q2, q3, q4, q5, q6, q7, xc);
      rsum += r;
      rv = (unsigned)__builtin_bit_cast(unsigned short, (_Float16)r);
      xc = xn;
    }
    {  // step kCT-1: uses xc, no prefetch across the barrier
      v4u q0, q1, q2, q3, q4, q5, q6, q7;
      STEP_LDS_NOX(q0, q1, q2, q3, q4, q5, q6, q7, rv);
      float r = tail(q0, q1, q2, q3, q4, q5, q6, q7, xc);
      rsum += r;
      rv = (unsigned)__builtin_bit_cast(unsigned short, (_Float16)r);
    }
    __syncthreads();  // done with this buffer
  }

  // right padding
  pad_step();
  pad_step();
  pad_step();

  // ---- epilogue: mean over Tp, FC (16x64) + ReLU (single wave) ----
  float* aggbuf = (float*)(smem + kAggOff);
  aggbuf[lane] = 1.0f - 2.0f * rsum * (1.0f / (float)kTp);
  if (lane < kO) {
    float acc = b_fc[lane];
    const float* wf = W_fc + lane * kH;
#pragma unroll
    for (int j = 0; j < kH; ++j)
      acc = fmaf(wf[j], aggbuf[j], acc);
    out[b * kO + lane] = fmaxf(acc, 0.0f);
  }
}

extern "C" void kernel_launch(void* const* d_in, const int* in_sizes, int n_in,
                              void* d_out, int out_size, void* d_ws, size_t ws_size,
                              hipStream_t stream) {
  const float* x    = (const float*)d_in[0];
  const float* W_ih = (const float*)d_in[1];
  const float* W_hh = (const float*)d_in[2];
  const float* b_ih = (const float*)d_in[3];
  const float* b_hh = (const float*)d_in[4];
  const float* W_fc = (const float*)d_in[5];
  const float* b_fc = (const float*)d_in[6];
  float* out = (float*)d_out;

  rnn_fused<<<dim3(kB), dim3(128), kSmemBytes, stream>>>(
      x, W_ih, W_hh, b_ih, b_hh, W_fc, b_fc, out);
}